// Round 5
// baseline (1694.347 us; speedup 1.0000x reference)
//
#include <hip/hip_runtime.h>

// ConvexPolytopeManifold: dual-PGD QP projection. B=4096, n=512, m=1024.
// Round 5 (= round 4 with compile fix):
//  - 64x64 wave tile (32 FLOP/LDS-byte, vs 21 for 64x32) -> LDS-BW relief
//  - 128-thread blocks (2 waves), tile 128Mx64N, grid 512 = 2 blocks/CU
//  - memsets + first PGD iteration of each phase folded into the c / masked
//    GEMM epilogues (lam1 = step*relu(c), lam1 = step*relu(masked)) — exact
//
// math:
//   Q = A@A^T; y = x+u; c = y@A^T - b
//   lam1 = step*relu(c); 49x lam = relu(lam - 0.01*(lam@Q - c))
//   active = (c - lam@Q >= -TOL)
//   masked = (u@A^T) * active; lam1 = step*relu(masked)
//   9x lam = relu(lam - 0.01*(lam@Q - masked)) * active
//   out = u - lam@A

#define TOLV 1e-5f
#define STEPV 0.01f

typedef __attribute__((ext_vector_type(8))) short short8;
typedef __attribute__((ext_vector_type(4))) float floatx4;
typedef unsigned short ushort_t;

#define GLDS(gptr, lptr) \
    __builtin_amdgcn_global_load_lds( \
        (const __attribute__((address_space(1))) void*)(gptr), \
        (__attribute__((address_space(3))) void*)(lptr), 16, 0, 0)

__device__ inline ushort_t f2bf(float f) {
    union { float f; unsigned int u; } c; c.f = f;
    unsigned int u = c.u;
    return (ushort_t)((u + 0x7FFFu + ((u >> 16) & 1u)) >> 16);   // RNE
}
__device__ inline float bf2f(ushort_t h) {
    union { unsigned int u; float f; } c; c.u = ((unsigned int)h) << 16;
    return c.f;
}

__global__ void addcast_kernel(const float* __restrict__ x, const float* __restrict__ u,
                               ushort_t* __restrict__ ybf, ushort_t* __restrict__ ubf, int n) {
    int idx = (blockIdx.x * blockDim.x + threadIdx.x) * 4;
    if (idx < n) {
        float4 xv = *(const float4*)(x + idx);
        float4 uv = *(const float4*)(u + idx);
        ushort4 yo, uo;
        yo.x = f2bf(xv.x + uv.x); yo.y = f2bf(xv.y + uv.y);
        yo.z = f2bf(xv.z + uv.z); yo.w = f2bf(xv.w + uv.w);
        uo.x = f2bf(uv.x); uo.y = f2bf(uv.y); uo.z = f2bf(uv.z); uo.w = f2bf(uv.w);
        *(ushort4*)(ybf + idx) = yo;
        *(ushort4*)(ubf + idx) = uo;
    }
}

__global__ void cvt_bf16_kernel(const float* __restrict__ src, ushort_t* __restrict__ dst, int n) {
    int idx = (blockIdx.x * blockDim.x + threadIdx.x) * 4;
    if (idx < n) {
        float4 v = *(const float4*)(src + idx);
        ushort4 o;
        o.x = f2bf(v.x); o.y = f2bf(v.y); o.z = f2bf(v.z); o.w = f2bf(v.w);
        *(ushort4*)(dst + idx) = o;
    }
}

__global__ void transpose_cast_kernel(const float* __restrict__ A, ushort_t* __restrict__ AT,
                                      int m, int n) {
    __shared__ float t[32][33];
    int bx = blockIdx.x * 32;
    int by = blockIdx.y * 32;
    int tx = threadIdx.x & 31, ty = threadIdx.x >> 5;   // 32 x 8
#pragma unroll
    for (int i = 0; i < 32; i += 8)
        t[ty + i][tx] = A[(size_t)(by + ty + i) * n + bx + tx];
    __syncthreads();
#pragma unroll
    for (int i = 0; i < 32; i += 8)
        AT[(size_t)(bx + ty + i) * m + by + tx] = f2bf(t[tx][ty + i]);
}

// ---------------- bf16 MFMA GEMM:  C = X @ W^T ----------------
// X=[M,K] bf16, W=[N,K] bf16. Block: 128 threads = 2 waves.
// Tile 128(M) x 64(N), BK=64. Wave tile 64x64 (4x4 of 16x16x32).
// XOR-swizzled LDS: physical slot s of row r holds global chunk s^(r&7).
// EPI: 0 Q: outH=bf16(v)
//      1 c+lam1: outF=v-bvec[col]; l=STEP*relu(outF); outF2=l; outH=bf16(l)
//      2 iter:   l=relu(e0-STEP*(v-e1)); outF=l; outH=bf16(l)
//      3 iter*act
//      4 act:    outH = (e1 - v >= -TOL) ? 1 : 0  (bf16)
//      5 masked+lam1: mv=v*act; outF=mv; l=STEP*relu(mv); outF2=l; outH=bf16(l)
//      6 final:  outF = e0 - v
template<int EPI>
__global__ __launch_bounds__(128)
void mfma_g(const ushort_t* __restrict__ X, const ushort_t* __restrict__ W,
            const float* __restrict__ e0, const float* __restrict__ e1,
            const ushort_t* __restrict__ actb,
            float* __restrict__ outF, float* __restrict__ outF2,
            ushort_t* __restrict__ outH,
            const float* __restrict__ bvec,
            int M, int N, int K) {
    __shared__ short As[128 * 64];   // 16 KB
    __shared__ short Bs[64 * 64];    //  8 KB

    const int tid = threadIdx.x;
    const int w = tid >> 6;          // 0..1
    const int lane = tid & 63;
    const int bm = blockIdx.x * 128;
    const int bn = blockIdx.y * 64;
    const int wm = w * 64;           // wave covers rows wm..wm+63, all 64 cols
    const int quad = lane >> 4;
    const int l15 = lane & 15;

    const int ldr = lane >> 3;                  // 0..7
    const int csw = ((lane & 7) ^ ldr) * 8;     // swizzled source chunk (elems)

    floatx4 acc[4][4] = {};

    for (int k0 = 0; k0 < K; k0 += 64) {
        // stage A: 128 rows; wave w covers rows w*64 .. w*64+63 (8 issues)
#pragma unroll
        for (int t = 0; t < 8; ++t) {
            int row = w * 64 + t * 8 + ldr;
            const ushort_t* ga = X + (size_t)(bm + row) * K + k0 + csw;
            short* la = As + (w * 64 + t * 8) * 64;     // wave-uniform base
            GLDS(ga, la);
        }
        // stage B: 64 rows; wave w covers rows w*32 .. w*32+31 (4 issues)
#pragma unroll
        for (int t = 0; t < 4; ++t) {
            int row = w * 32 + t * 8 + ldr;
            const ushort_t* gb = W + (size_t)(bn + row) * K + k0 + csw;
            short* lb = Bs + (w * 32 + t * 8) * 64;
            GLDS(gb, lb);
        }
        __syncthreads();
#pragma unroll
        for (int kk = 0; kk < 2; ++kk) {
            const int sw = ((kk * 4 + quad) ^ (l15 & 7)) * 8;   // de-swizzle
            short8 af[4], bfr[4];
#pragma unroll
            for (int i = 0; i < 4; ++i)
                af[i] = *(const short8*)(As + (wm + i * 16 + l15) * 64 + sw);
#pragma unroll
            for (int i = 0; i < 4; ++i)
                bfr[i] = *(const short8*)(Bs + (i * 16 + l15) * 64 + sw);
#pragma unroll
            for (int mt = 0; mt < 4; ++mt)
#pragma unroll
                for (int nt = 0; nt < 4; ++nt)
                    acc[mt][nt] = __builtin_amdgcn_mfma_f32_16x16x32_bf16(
                        af[mt], bfr[nt], acc[mt][nt], 0, 0, 0);
        }
        __syncthreads();
    }

    // C/D layout: row = quad*4 + r, col = lane&15 within each 16x16 tile
#pragma unroll
    for (int mt = 0; mt < 4; ++mt) {
#pragma unroll
        for (int nt = 0; nt < 4; ++nt) {
#pragma unroll
            for (int r = 0; r < 4; ++r) {
                int row = bm + wm + mt * 16 + quad * 4 + r;
                int col = bn + nt * 16 + l15;
                size_t idx = (size_t)row * N + col;
                float v = acc[mt][nt][r];
                if (EPI == 0) {
                    outH[idx] = f2bf(v);
                } else if (EPI == 1) {
                    float cv = v - bvec[col];
                    outF[idx] = cv;
                    float l = STEPV * fmaxf(cv, 0.0f);
                    outF2[idx] = l;
                    outH[idx] = f2bf(l);
                } else if (EPI == 2) {
                    float nv = fmaxf(fmaf(-STEPV, v - e1[idx], e0[idx]), 0.0f);
                    outF[idx] = nv;
                    outH[idx] = f2bf(nv);
                } else if (EPI == 3) {
                    float nv = fmaxf(fmaf(-STEPV, v - e1[idx], e0[idx]), 0.0f) * bf2f(actb[idx]);
                    outF[idx] = nv;
                    outH[idx] = f2bf(nv);
                } else if (EPI == 4) {
                    outH[idx] = (e1[idx] - v >= -TOLV) ? (ushort_t)0x3F80 : (ushort_t)0;
                } else if (EPI == 5) {
                    float mv = v * bf2f(actb[idx]);
                    outF[idx] = mv;
                    float l = STEPV * fmaxf(mv, 0.0f);
                    outF2[idx] = l;
                    outH[idx] = f2bf(l);
                } else if (EPI == 6) {
                    outF[idx] = e0[idx] - v;
                }
            }
        }
    }
}

extern "C" void kernel_launch(void* const* d_in, const int* in_sizes, int n_in,
                              void* d_out, int out_size, void* d_ws, size_t ws_size,
                              hipStream_t stream) {
    const float* x = (const float*)d_in[0];  // [B,n]
    const float* u = (const float*)d_in[1];  // [B,n]
    const float* A = (const float*)d_in[2];  // [m,n]
    const float* b = (const float*)d_in[3];  // [m]
    float* out = (float*)d_out;              // [B,n]

    const int B = 4096, n = 512, m = 1024;
    const size_t Bm = (size_t)B * m;
    const size_t Bn = (size_t)B * n;

    ushort_t* A_bf   = (ushort_t*)d_ws;            // [m,n]
    ushort_t* AT_bf  = A_bf + (size_t)m * n;       // [n,m]
    ushort_t* y_bf   = AT_bf + (size_t)n * m;      // [B,n]
    ushort_t* u_bf   = y_bf + Bn;                  // [B,n]
    ushort_t* Qbf    = u_bf + Bn;                  // [m,m]
    ushort_t* lamH_A = Qbf + (size_t)m * m;        // [B,m]
    ushort_t* lamH_B = lamH_A + Bm;                // [B,m]
    ushort_t* act    = lamH_B + Bm;                // [B,m]
    float* cbuf   = (float*)(act + Bm);            // [B,m]
    float* lamF_A = cbuf + Bm;                     // [B,m]
    float* lamF_B = lamF_A + Bm;                   // [B,m]

    dim3 blk(128);

    addcast_kernel<<<(int)(Bn / 4 + 255) / 256, 256, 0, stream>>>(x, u, y_bf, u_bf, (int)Bn);
    cvt_bf16_kernel<<<(m * n / 4 + 255) / 256, 256, 0, stream>>>(A, A_bf, m * n);
    transpose_cast_kernel<<<dim3(n / 32, m / 32), dim3(256), 0, stream>>>(A, AT_bf, m, n);

    // Q = bf16(A @ A^T)
    mfma_g<0><<<dim3(m / 128, m / 64), blk, 0, stream>>>(
        A_bf, A_bf, nullptr, nullptr, nullptr, nullptr, nullptr, Qbf, nullptr, m, m, n);

    // c = y @ A^T - b; lam1 = step*relu(c)
    mfma_g<1><<<dim3(B / 128, m / 64), blk, 0, stream>>>(
        y_bf, A_bf, nullptr, nullptr, nullptr, cbuf, lamF_A, lamH_A, b, B, m, n);

    // phase 1: 49 more iterations
    float* lfin = lamF_A; float* lfout = lamF_B;
    ushort_t* lhin = lamH_A; ushort_t* lhout = lamH_B;
    for (int it = 0; it < 49; ++it) {
        mfma_g<2><<<dim3(B / 128, m / 64), blk, 0, stream>>>(
            lhin, Qbf, lfin, cbuf, nullptr, lfout, nullptr, lhout, nullptr, B, m, m);
        float* tf = lfin; lfin = lfout; lfout = tf;
        ushort_t* th = lhin; lhin = lhout; lhout = th;
    }

    // active = (c - lam@Q >= -TOL)
    mfma_g<4><<<dim3(B / 128, m / 64), blk, 0, stream>>>(
        lhin, Qbf, nullptr, cbuf, nullptr, nullptr, nullptr, act, nullptr, B, m, m);

    // masked = (u @ A^T) * active -> cbuf; lam1 = step*relu(masked)
    mfma_g<5><<<dim3(B / 128, m / 64), blk, 0, stream>>>(
        u_bf, A_bf, nullptr, nullptr, act, cbuf, lamF_A, lamH_A, nullptr, B, m, n);

    // phase 2: 9 more iterations
    lfin = lamF_A; lfout = lamF_B; lhin = lamH_A; lhout = lamH_B;
    for (int it = 0; it < 9; ++it) {
        mfma_g<3><<<dim3(B / 128, m / 64), blk, 0, stream>>>(
            lhin, Qbf, lfin, cbuf, act, lfout, nullptr, lhout, nullptr, B, m, m);
        float* tf = lfin; lfin = lfout; lfout = tf;
        ushort_t* th = lhin; lhin = lhout; lhout = th;
    }

    // out = u - lam @ A
    mfma_g<6><<<dim3(B / 128, n / 64), blk, 0, stream>>>(
        lhin, AT_bf, u, nullptr, nullptr, out, nullptr, nullptr, nullptr, B, n, m);
}

// Round 6
// 1462.258 us; speedup vs baseline: 1.1587x; 1.1587x over previous
//
#include <hip/hip_runtime.h>

// ConvexPolytopeManifold: dual-PGD QP projection. B=4096, n=512, m=1024.
// Round 6:
//  - tile 64Mx128N (256 thr, 4 waves, wave tile 32x64): halves lam-strip
//    logical re-reads (8 column-blocks instead of 16); 512 blocks = 2/CU
//  - XCD-aware block swizzle: all column-blocks of an M-strip on one XCD ->
//    lam + Q re-reads served from local L2 (3 MB footprint < 4 MB L2/XCD)
//  - numerics identical to round 5 (fp32 lam master + cbuf; bf16 MFMA)
//
// math:
//   Q = A@A^T; y = x+u; c = y@A^T - b
//   lam1 = step*relu(c); 49x lam = relu(lam - 0.01*(lam@Q - c))
//   active = (c - lam@Q >= -TOL)
//   masked = (u@A^T) * active; lam1 = step*relu(masked)
//   9x lam = relu(lam - 0.01*(lam@Q - masked)) * active
//   out = u - lam@A

#define TOLV 1e-5f
#define STEPV 0.01f

typedef __attribute__((ext_vector_type(8))) short short8;
typedef __attribute__((ext_vector_type(4))) float floatx4;
typedef unsigned short ushort_t;

#define GLDS(gptr, lptr) \
    __builtin_amdgcn_global_load_lds( \
        (const __attribute__((address_space(1))) void*)(gptr), \
        (__attribute__((address_space(3))) void*)(lptr), 16, 0, 0)

__device__ inline ushort_t f2bf(float f) {
    union { float f; unsigned int u; } c; c.f = f;
    unsigned int u = c.u;
    return (ushort_t)((u + 0x7FFFu + ((u >> 16) & 1u)) >> 16);   // RNE
}
__device__ inline float bf2f(ushort_t h) {
    union { unsigned int u; float f; } c; c.u = ((unsigned int)h) << 16;
    return c.f;
}

__global__ void addcast_kernel(const float* __restrict__ x, const float* __restrict__ u,
                               ushort_t* __restrict__ ybf, ushort_t* __restrict__ ubf, int n) {
    int idx = (blockIdx.x * blockDim.x + threadIdx.x) * 4;
    if (idx < n) {
        float4 xv = *(const float4*)(x + idx);
        float4 uv = *(const float4*)(u + idx);
        ushort4 yo, uo;
        yo.x = f2bf(xv.x + uv.x); yo.y = f2bf(xv.y + uv.y);
        yo.z = f2bf(xv.z + uv.z); yo.w = f2bf(xv.w + uv.w);
        uo.x = f2bf(uv.x); uo.y = f2bf(uv.y); uo.z = f2bf(uv.z); uo.w = f2bf(uv.w);
        *(ushort4*)(ybf + idx) = yo;
        *(ushort4*)(ubf + idx) = uo;
    }
}

__global__ void cvt_bf16_kernel(const float* __restrict__ src, ushort_t* __restrict__ dst, int n) {
    int idx = (blockIdx.x * blockDim.x + threadIdx.x) * 4;
    if (idx < n) {
        float4 v = *(const float4*)(src + idx);
        ushort4 o;
        o.x = f2bf(v.x); o.y = f2bf(v.y); o.z = f2bf(v.z); o.w = f2bf(v.w);
        *(ushort4*)(dst + idx) = o;
    }
}

__global__ void transpose_cast_kernel(const float* __restrict__ A, ushort_t* __restrict__ AT,
                                      int m, int n) {
    __shared__ float t[32][33];
    int bx = blockIdx.x * 32;
    int by = blockIdx.y * 32;
    int tx = threadIdx.x & 31, ty = threadIdx.x >> 5;   // 32 x 8
#pragma unroll
    for (int i = 0; i < 32; i += 8)
        t[ty + i][tx] = A[(size_t)(by + ty + i) * n + bx + tx];
    __syncthreads();
#pragma unroll
    for (int i = 0; i < 32; i += 8)
        AT[(size_t)(bx + ty + i) * m + by + tx] = f2bf(t[tx][ty + i]);
}

// ---------------- bf16 MFMA GEMM:  C = X @ W^T ----------------
// X=[M,K] bf16, W=[N,K] bf16. 256 threads = 4 waves.
// Tile 64(M) x 128(N), BK=64. Wave tile 32x64 (2x4 of 16x16x32).
// XOR-swizzled LDS: physical chunk s of row r holds global chunk s^(r&7).
// 1D grid with XCD swizzle: requires (M/64) % 8 == 0 OR handles it generically
// when nbm % 8 == 0 (true for all our shapes: 16 or 64).
// EPI: 0 Q: outH=bf16(v)
//      1 c+lam1: cv=v-bvec[col]; outF=cv; l=STEP*relu(cv); outF2=l; outH=bf16(l)
//      2 iter:   l=relu(e0-STEP*(v-e1)); outF=l; outH=bf16(l)
//      3 iter*act
//      4 act:    outH = (e1 - v >= -TOL) ? 1 : 0  (bf16)
//      5 masked+lam1: mv=v*act; outF=mv; l=STEP*relu(mv); outF2=l; outH=bf16(l)
//      6 final:  outF = e0 - v
template<int EPI>
__global__ __launch_bounds__(256)
void mfma_g(const ushort_t* __restrict__ X, const ushort_t* __restrict__ W,
            const float* __restrict__ e0, const float* __restrict__ e1,
            const ushort_t* __restrict__ actb,
            float* __restrict__ outF, float* __restrict__ outF2,
            ushort_t* __restrict__ outH,
            const float* __restrict__ bvec,
            int M, int N, int K) {
    __shared__ short As[64 * 64];    //  8 KB
    __shared__ short Bs[128 * 64];   // 16 KB

    const int tid = threadIdx.x;
    const int w = tid >> 6;          // 0..3
    const int lane = tid & 63;

    // XCD-aware block mapping: nbm strips, nbn column-blocks; strips of one
    // XCD get all their column-blocks locally (L2 reuse of X-strip and Q).
    const int nbm = M >> 6;
    const int spx = nbm >> 3;                 // strips per XCD (nbm % 8 == 0)
    const int xcd = blockIdx.x & 7;
    const int loc = blockIdx.x >> 3;
    const int bm = (xcd * spx + (loc % spx)) << 6;
    const int bn = (loc / spx) << 7;

    const int wm = (w & 1) * 32;     // wave row offset
    const int wn = (w >> 1) * 64;    // wave col offset
    const int quad = lane >> 4;
    const int l15 = lane & 15;

    const int ldr = lane >> 3;                  // 0..7
    const int csw = ((lane & 7) ^ ldr) * 8;     // swizzled source chunk (elems)

    floatx4 acc[2][4] = {};

    for (int k0 = 0; k0 < K; k0 += 64) {
        // stage A: 64 rows; wave w covers rows w*16 .. w*16+15 (2 issues)
#pragma unroll
        for (int t = 0; t < 2; ++t) {
            int row = w * 16 + t * 8 + ldr;
            const ushort_t* ga = X + (size_t)(bm + row) * K + k0 + csw;
            short* la = As + (w * 16 + t * 8) * 64;     // wave-uniform base
            GLDS(ga, la);
        }
        // stage B: 128 rows; wave w covers rows w*32 .. w*32+31 (4 issues)
#pragma unroll
        for (int t = 0; t < 4; ++t) {
            int row = w * 32 + t * 8 + ldr;
            const ushort_t* gb = W + (size_t)(bn + row) * K + k0 + csw;
            short* lb = Bs + (w * 32 + t * 8) * 64;
            GLDS(gb, lb);
        }
        __syncthreads();
#pragma unroll
        for (int kk = 0; kk < 2; ++kk) {
            const int sw = ((kk * 4 + quad) ^ (l15 & 7)) * 8;   // de-swizzle
            short8 af[2], bfr[4];
#pragma unroll
            for (int i = 0; i < 2; ++i)
                af[i] = *(const short8*)(As + (wm + i * 16 + l15) * 64 + sw);
#pragma unroll
            for (int i = 0; i < 4; ++i)
                bfr[i] = *(const short8*)(Bs + (wn + i * 16 + l15) * 64 + sw);
#pragma unroll
            for (int mt = 0; mt < 2; ++mt)
#pragma unroll
                for (int nt = 0; nt < 4; ++nt)
                    acc[mt][nt] = __builtin_amdgcn_mfma_f32_16x16x32_bf16(
                        af[mt], bfr[nt], acc[mt][nt], 0, 0, 0);
        }
        __syncthreads();
    }

    // C/D layout: row = quad*4 + r, col = lane&15 within each 16x16 tile
#pragma unroll
    for (int mt = 0; mt < 2; ++mt) {
#pragma unroll
        for (int nt = 0; nt < 4; ++nt) {
#pragma unroll
            for (int r = 0; r < 4; ++r) {
                int row = bm + wm + mt * 16 + quad * 4 + r;
                int col = bn + wn + nt * 16 + l15;
                size_t idx = (size_t)row * N + col;
                float v = acc[mt][nt][r];
                if (EPI == 0) {
                    outH[idx] = f2bf(v);
                } else if (EPI == 1) {
                    float cv = v - bvec[col];
                    outF[idx] = cv;
                    float l = STEPV * fmaxf(cv, 0.0f);
                    outF2[idx] = l;
                    outH[idx] = f2bf(l);
                } else if (EPI == 2) {
                    float nv = fmaxf(fmaf(-STEPV, v - e1[idx], e0[idx]), 0.0f);
                    outF[idx] = nv;
                    outH[idx] = f2bf(nv);
                } else if (EPI == 3) {
                    float nv = fmaxf(fmaf(-STEPV, v - e1[idx], e0[idx]), 0.0f) * bf2f(actb[idx]);
                    outF[idx] = nv;
                    outH[idx] = f2bf(nv);
                } else if (EPI == 4) {
                    outH[idx] = (e1[idx] - v >= -TOLV) ? (ushort_t)0x3F80 : (ushort_t)0;
                } else if (EPI == 5) {
                    float mv = v * bf2f(actb[idx]);
                    outF[idx] = mv;
                    float l = STEPV * fmaxf(mv, 0.0f);
                    outF2[idx] = l;
                    outH[idx] = f2bf(l);
                } else if (EPI == 6) {
                    outF[idx] = e0[idx] - v;
                }
            }
        }
    }
}

static inline int grid1d(int M, int N) { return (M >> 6) * (N >> 7); }

extern "C" void kernel_launch(void* const* d_in, const int* in_sizes, int n_in,
                              void* d_out, int out_size, void* d_ws, size_t ws_size,
                              hipStream_t stream) {
    const float* x = (const float*)d_in[0];  // [B,n]
    const float* u = (const float*)d_in[1];  // [B,n]
    const float* A = (const float*)d_in[2];  // [m,n]
    const float* b = (const float*)d_in[3];  // [m]
    float* out = (float*)d_out;              // [B,n]

    const int B = 4096, n = 512, m = 1024;
    const size_t Bm = (size_t)B * m;
    const size_t Bn = (size_t)B * n;

    ushort_t* A_bf   = (ushort_t*)d_ws;            // [m,n]
    ushort_t* AT_bf  = A_bf + (size_t)m * n;       // [n,m]
    ushort_t* y_bf   = AT_bf + (size_t)n * m;      // [B,n]
    ushort_t* u_bf   = y_bf + Bn;                  // [B,n]
    ushort_t* Qbf    = u_bf + Bn;                  // [m,m]
    ushort_t* lamH_A = Qbf + (size_t)m * m;        // [B,m]
    ushort_t* lamH_B = lamH_A + Bm;                // [B,m]
    ushort_t* act    = lamH_B + Bm;                // [B,m]
    float* cbuf   = (float*)(act + Bm);            // [B,m]
    float* lamF_A = cbuf + Bm;                     // [B,m]
    float* lamF_B = lamF_A + Bm;                   // [B,m]

    dim3 blk(256);

    addcast_kernel<<<(int)(Bn / 4 + 255) / 256, 256, 0, stream>>>(x, u, y_bf, u_bf, (int)Bn);
    cvt_bf16_kernel<<<(m * n / 4 + 255) / 256, 256, 0, stream>>>(A, A_bf, m * n);
    transpose_cast_kernel<<<dim3(n / 32, m / 32), dim3(256), 0, stream>>>(A, AT_bf, m, n);

    // Q = bf16(A @ A^T)
    mfma_g<0><<<grid1d(m, m), blk, 0, stream>>>(
        A_bf, A_bf, nullptr, nullptr, nullptr, nullptr, nullptr, Qbf, nullptr, m, m, n);

    // c = y @ A^T - b; lam1 = step*relu(c)
    mfma_g<1><<<grid1d(B, m), blk, 0, stream>>>(
        y_bf, A_bf, nullptr, nullptr, nullptr, cbuf, lamF_A, lamH_A, b, B, m, n);

    // phase 1: 49 more iterations
    float* lfin = lamF_A; float* lfout = lamF_B;
    ushort_t* lhin = lamH_A; ushort_t* lhout = lamH_B;
    for (int it = 0; it < 49; ++it) {
        mfma_g<2><<<grid1d(B, m), blk, 0, stream>>>(
            lhin, Qbf, lfin, cbuf, nullptr, lfout, nullptr, lhout, nullptr, B, m, m);
        float* tf = lfin; lfin = lfout; lfout = tf;
        ushort_t* th = lhin; lhin = lhout; lhout = th;
    }

    // active = (c - lam@Q >= -TOL)
    mfma_g<4><<<grid1d(B, m), blk, 0, stream>>>(
        lhin, Qbf, nullptr, cbuf, nullptr, nullptr, nullptr, act, nullptr, B, m, m);

    // masked = (u @ A^T) * active -> cbuf; lam1 = step*relu(masked)
    mfma_g<5><<<grid1d(B, m), blk, 0, stream>>>(
        u_bf, A_bf, nullptr, nullptr, act, cbuf, lamF_A, lamH_A, nullptr, B, m, n);

    // phase 2: 9 more iterations
    lfin = lamF_A; lfout = lamF_B; lhin = lamH_A; lhout = lamH_B;
    for (int it = 0; it < 9; ++it) {
        mfma_g<3><<<grid1d(B, m), blk, 0, stream>>>(
            lhin, Qbf, lfin, cbuf, act, lfout, nullptr, lhout, nullptr, B, m, m);
        float* tf = lfin; lfin = lfout; lfout = tf;
        ushort_t* th = lhin; lhin = lhout; lhout = th;
    }

    // out = u - lam @ A
    mfma_g<6><<<grid1d(B, n), blk, 0, stream>>>(
        lhin, AT_bf, u, nullptr, nullptr, out, nullptr, nullptr, nullptr, B, n, m);
}